// Round 2
// baseline (10197.691 us; speedup 1.0000x reference)
//
#include <hip/hip_runtime.h>
#include <math.h>

#define MAXB 3008
#define T 256
#define BPT 12   // ceil(3000/256) boxes per thread

// ---------------- kernel 0: global max over all box coordinates ----------------
__global__ void max_kernel(const float* __restrict__ boxes, int n4,
                           float* __restrict__ out_max) {
    __shared__ float red[256];
    float m = -1e30f;
    for (int i = threadIdx.x; i < n4; i += 256) m = fmaxf(m, boxes[i]);
    red[threadIdx.x] = m;
    __syncthreads();
    for (int s = 128; s > 0; s >>= 1) {
        if (threadIdx.x < s) red[threadIdx.x] = fmaxf(red[threadIdx.x], red[threadIdx.x + s]);
        __syncthreads();
    }
    if (threadIdx.x == 0) out_max[0] = red[0];
}

// ---------------- kernel 1: exact f32 emulation of the reference scan ----------------
// Single block. Mirrors the jax/np float32 algorithm op-for-op, including the
// slot-swap permutation (argmax tie-break = lowest CURRENT slot, like np.argmax
// over the -inf-masked, swap-permuted score array).
__global__ void __launch_bounds__(T)
nms_full_kernel(const float* __restrict__ boxes, const float* __restrict__ scores,
                const int* __restrict__ idxs, const float* __restrict__ maxc_p,
                float* __restrict__ out, int n) {
#pragma clang fp contract(off)
    const int tid = threadIdx.x;
    __shared__ float sscore[MAXB];          // box-indexed current scores
    __shared__ unsigned short s2b[MAXB];    // slot -> box id
    __shared__ unsigned long long red[T / 64];
    __shared__ unsigned long long bkey;
    __shared__ float bwb[5];                // winner box x1,y1,x2,y2 + class

    const float maxcp1 = maxc_p[0] + 1.0f;  // f32, matches (max_coord + 1.0)

    // registers: this thread's boxes (offset in f32, matching ref rounding)
    float bx0[BPT], bx1[BPT], bx2[BPT], bx3[BPT], bcls[BPT];
#pragma unroll
    for (int k = 0; k < BPT; k++) {
        int b = tid + k * T;
        if (b < n) {
            float cf = (float)idxs[b];
            float off = cf * maxcp1;                    // f32 mul
            float4 bb = ((const float4*)boxes)[b];
            bx0[k] = bb.x + off;                        // f32 adds (no fma)
            bx1[k] = bb.y + off;
            bx2[k] = bb.z + off;
            bx3[k] = bb.w + off;
            bcls[k] = cf;
            sscore[b] = scores[b];
            s2b[b] = (unsigned short)b;
        } else {
            bcls[k] = -1.0f;
        }
    }

    const int wid = tid >> 6, lane = tid & 63;

    for (int i = 0; i < n; i++) {
        __syncthreads();  // B1: prior decay / s2b writes (and init) visible

        // ---- argmax over slots [i, n): key = (score_bits << 32) | (n - slot)
        // score >= 0 always -> f32 bits monotonic; low field breaks ties toward
        // the LOWEST slot (numpy argmax-first semantics).
        unsigned short bs[BPT];
        float sc[BPT];
#pragma unroll
        for (int k = 0; k < BPT; k++) {
            int s = i + tid + k * T;
            bs[k] = (s < n) ? s2b[s] : 0;
        }
#pragma unroll
        for (int k = 0; k < BPT; k++) {
            int s = i + tid + k * T;
            sc[k] = (s < n) ? sscore[bs[k]] : -1.0f;
        }
        unsigned long long kmax = 0ull;
#pragma unroll
        for (int k = 0; k < BPT; k++) {
            int s = i + tid + k * T;
            if (s < n) {
                unsigned long long key =
                    ((unsigned long long)__float_as_uint(sc[k]) << 32) |
                    (unsigned int)(n - s);
                kmax = kmax > key ? kmax : key;
            }
        }
        for (int o = 32; o >= 1; o >>= 1) {
            unsigned long long other = __shfl_xor(kmax, o, 64);
            kmax = kmax > other ? kmax : other;
        }
        if (lane == 0) red[wid] = kmax;
        __syncthreads();  // B2
        if (wid == 0) {
            unsigned long long kk = (lane < T / 64) ? red[lane] : 0ull;
            for (int o = 32; o >= 1; o >>= 1) {
                unsigned long long other = __shfl_xor(kk, o, 64);
                kk = kk > other ? kk : other;
            }
            if (lane == 0) bkey = kk;
        }
        __syncthreads();  // B3

        unsigned long long key = bkey;
        int j = n - (int)(key & 0xffffffffu);            // winner slot
        float best = __uint_as_float((unsigned int)(key >> 32));
        int w = s2b[j];                                  // winner box id (broadcast read)

        if (tid == (w & (T - 1))) {                      // owner publishes winner box
            int kw = w >> 8;
#pragma unroll
            for (int k = 0; k < BPT; k++)
                if (k == kw) {
                    bwb[0] = bx0[k]; bwb[1] = bx1[k];
                    bwb[2] = bx2[k]; bwb[3] = bx3[k];
                    bwb[4] = bcls[k];
                }
        }
        int s2b_i = 0;
        if (tid == 0) {
            s2b_i = s2b[i];                              // displaced box (pre-swap slot i)
            out[i]         = best;                       // frozen score at slot i
            out[n + i]     = (float)w;                   // order: original index
            out[2 * n + i] = (best > 0.05f) ? 1.0f : 0.0f;
        }
        __syncthreads();  // B4: bwb published, s2b reads done

        // ---- gaussian decay: all unselected boxes except winner.
        // Cross-class IoU is exactly 0 in f32 (gap >= 1 - 2*ulp) -> decay = 1.0
        // exactly -> safe to skip. Previously-selected same-class boxes get
        // harmlessly updated (their scores are never read again).
        float w0 = bwb[0], w1 = bwb[1], w2 = bwb[2], w3 = bwb[3], wcls = bwb[4];
        float area_w = (w2 - w0) * (w3 - w1);
#pragma unroll
        for (int k = 0; k < BPT; k++) {
            int b = tid + k * T;
            if (bcls[k] == wcls && b != w) {
                float x1 = fmaxf(w0, bx0[k]);
                float y1 = fmaxf(w1, bx1[k]);
                float x2 = fminf(w2, bx2[k]);
                float y2 = fminf(w3, bx3[k]);
                float iw = fmaxf(x2 - x1, 0.0f);
                float ih = fmaxf(y2 - y1, 0.0f);
                float inter = iw * ih;
                float area_b = (bx2[k] - bx0[k]) * (bx3[k] - bx1[k]);
                float iou = inter / ((area_w + area_b) - inter);
                float arg = -(iou * iou) / 0.5f;
                float decay = (float)exp((double)arg);   // ~correctly-rounded f32 exp
                sscore[b] = sscore[b] * decay;
            }
        }
        if (tid == 0) s2b[j] = (unsigned short)s2b_i;    // complete the swap
    }
}

extern "C" void kernel_launch(void* const* d_in, const int* in_sizes, int n_in,
                              void* d_out, int out_size, void* d_ws, size_t ws_size,
                              hipStream_t stream) {
    const float* boxes  = (const float*)d_in[0];  // [N,4] f32
    const float* scores = (const float*)d_in[1];  // [N]   f32
    const int*   idxs   = (const int*)d_in[2];    // [N]   i32
    float* out = (float*)d_out;                   // scores | order | keep (f32)
    const int n = in_sizes[1];

    float* maxc = (float*)d_ws;

    max_kernel<<<1, 256, 0, stream>>>(boxes, n * 4, maxc);
    nms_full_kernel<<<1, T, 0, stream>>>(boxes, scores, idxs, maxc, out, n);
}

// Round 3
// 1980.099 us; speedup vs baseline: 5.1501x; 5.1501x over previous
//
#include <hip/hip_runtime.h>
#include <math.h>

#define NMAX 3008
#define CAPC 128
#define NCLS 80

// ---- workspace layout (bytes) ----
#define WS_MAXC   0                         // float
#define WS_FLAG   4                         // unsigned
#define WS_FSCORE 16                        // float[NMAX]   frozen score by box
#define WS_RANK   (WS_FSCORE + 4*NMAX)      // u16[NMAX]     provisional rank by box
#define WS_SSCORE (WS_RANK + 2*NMAX + 16)   // float[80*CAPC] per-class stream scores
#define WS_SBOX   (WS_SSCORE + 4*NCLS*CAPC) // u16[80*CAPC]  per-class stream box ids
#define WS_CNT    (WS_SBOX + 2*NCLS*CAPC)   // u16[80]       per-class counts

// ---------------- kernel 0: global max coord + flag init ----------------
__global__ void max_kernel(const float* __restrict__ boxes, int n4,
                           char* __restrict__ ws) {
    __shared__ float red[256];
    float m = -1e30f;
    for (int i = threadIdx.x; i < n4; i += 256) m = fmaxf(m, boxes[i]);
    red[threadIdx.x] = m;
    __syncthreads();
    for (int s = 128; s > 0; s >>= 1) {
        if (threadIdx.x < s) red[threadIdx.x] = fmaxf(red[threadIdx.x], red[threadIdx.x + s]);
        __syncthreads();
    }
    if (threadIdx.x == 0) {
        *(float*)(ws + WS_MAXC) = red[0];
        *(unsigned*)(ws + WS_FLAG) = 0u;
    }
}

// ---------------- kernel 1: exact f32 per-class soft-NMS sims ----------------
// One wave per class. Bit-identical to the global sim's same-class operations:
// cross-class decay is exactly *1.0f in f32 (offset gap >= 1) so skipping it is
// exact. Within-class argmax tie-break: lowest member (= original) index.
__global__ void __launch_bounds__(64)
nms_class_kernel(const float* __restrict__ boxes, const float* __restrict__ scores,
                 const int* __restrict__ idxs, char* __restrict__ ws, int n) {
#pragma clang fp contract(off)
    const int c = blockIdx.x;
    const int lane = threadIdx.x;
    const float* maxc_p = (const float*)(ws + WS_MAXC);
    float* fscore = (float*)(ws + WS_FSCORE);
    float* sstream = (float*)(ws + WS_SSCORE);
    unsigned short* bstream = (unsigned short*)(ws + WS_SBOX);
    unsigned short* cntws = (unsigned short*)(ws + WS_CNT);

    __shared__ float mx0[CAPC], mx1[CAPC], mx2[CAPC], mx3[CAPC], msc[CAPC];
    __shared__ unsigned short mgid[CAPC];

    const float maxcp1 = maxc_p[0] + 1.0f;
    const float off = (float)c * maxcp1;        // same op order as the ref

    // compact this class's members (index-ordered) into LDS
    int base = 0;
    for (int k0 = 0; k0 < n; k0 += 64) {
        int k = k0 + lane;
        bool p = (k < n) && (idxs[k] == c);
        unsigned long long m = __ballot(p);
        if (p) {
            int pos = base + __popcll(m & ((1ull << lane) - 1ull));
            if (pos < CAPC) {
                float4 bb = ((const float4*)boxes)[k];
                mx0[pos] = bb.x + off; mx1[pos] = bb.y + off;
                mx2[pos] = bb.z + off; mx3[pos] = bb.w + off;
                msc[pos] = scores[k];
                mgid[pos] = (unsigned short)k;
            }
        }
        base += __popcll(m);
    }
    int cnt = base < CAPC ? base : CAPC;
    __syncthreads();

    // register fragments: member lane (t=0) and 64+lane (t=1)
    float sc0 = -1.f, sc1 = -1.f;
    float a0 = 0, a1 = 0, a2 = 0, a3 = 0, b0 = 0, b1 = 0, b2 = 0, b3 = 0;
    int g0 = 0, g1 = 0;
    if (lane < cnt) {
        sc0 = msc[lane];
        a0 = mx0[lane]; a1 = mx1[lane]; a2 = mx2[lane]; a3 = mx3[lane];
        g0 = mgid[lane];
    }
    if (64 + lane < cnt) {
        sc1 = msc[64 + lane];
        b0 = mx0[64 + lane]; b1 = mx1[64 + lane]; b2 = mx2[64 + lane]; b3 = mx3[64 + lane];
        g1 = mgid[64 + lane];
    }

    for (int s = 0; s < cnt; s++) {
        float M = fmaxf(sc0, sc1);
        for (int o = 32; o >= 1; o >>= 1) M = fmaxf(M, __shfl_xor(M, o, 64));
        // tie-break: lowest member index = prefer t=0 ballot, then lowest lane
        unsigned long long balA = __ballot(sc0 == M);
        int wm;
        if (balA) wm = __ffsll((unsigned long long)balA) - 1;
        else {
            unsigned long long balB = __ballot(sc1 == M);
            wm = 64 + __ffsll((unsigned long long)balB) - 1;
        }
        float w0 = mx0[wm], w1 = mx1[wm], w2 = mx2[wm], w3 = mx3[wm];
        if (wm == lane) {
            sstream[c * CAPC + s] = M; bstream[c * CAPC + s] = (unsigned short)g0;
            fscore[g0] = M; sc0 = -1.f;
        } else if (wm == 64 + lane) {
            sstream[c * CAPC + s] = M; bstream[c * CAPC + s] = (unsigned short)g1;
            fscore[g1] = M; sc1 = -1.f;
        }
        float area_w = (w2 - w0) * (w3 - w1);
        if (sc0 >= 0.f) {
            float x1 = fmaxf(w0, a0), y1 = fmaxf(w1, a1);
            float x2 = fminf(w2, a2), y2 = fminf(w3, a3);
            float iw = fmaxf(x2 - x1, 0.f), ih = fmaxf(y2 - y1, 0.f);
            float inter = iw * ih;
            float area_b = (a2 - a0) * (a3 - a1);
            float iou = inter / ((area_w + area_b) - inter);
            float arg = -(iou * iou) / 0.5f;
            sc0 = sc0 * (float)exp((double)arg);
        }
        if (sc1 >= 0.f) {
            float x1 = fmaxf(w0, b0), y1 = fmaxf(w1, b1);
            float x2 = fminf(w2, b2), y2 = fminf(w3, b3);
            float iw = fmaxf(x2 - x1, 0.f), ih = fmaxf(y2 - y1, 0.f);
            float inter = iw * ih;
            float area_b = (b2 - b0) * (b3 - b1);
            float iou = inter / ((area_w + area_b) - inter);
            float arg = -(iou * iou) / 0.5f;
            sc1 = sc1 * (float)exp((double)arg);
        }
    }
    if (lane == 0) cntws[c] = (unsigned short)cnt;
}

// ---------------- kernel 2: provisional ranks + cross-class tie detection ----------------
__global__ void __launch_bounds__(256)
rank_detect_kernel(const int* __restrict__ idxs, char* __restrict__ ws, int n) {
    __shared__ float sv[NMAX];
    __shared__ unsigned short scls[NMAX];
    const float* fscore = (const float*)(ws + WS_FSCORE);
    unsigned short* rank = (unsigned short*)(ws + WS_RANK);
    unsigned* flag = (unsigned*)(ws + WS_FLAG);
    const int tid = threadIdx.x;
    for (int j = tid; j < n; j += 256) { sv[j] = fscore[j]; scls[j] = (unsigned short)idxs[j]; }
    __syncthreads();
    int i = blockIdx.x * 256 + tid;
    if (i < n) {
        float s = sv[i];
        int c = scls[i], r = 0, tie = 0;
        for (int j = 0; j < n; j++) {
            float x = sv[j];
            r += (x > s || (x == s && j < i)) ? 1 : 0;
            tie |= (x == s && scls[j] != c) ? 1 : 0;
        }
        rank[i] = (unsigned short)r;
        if (tie) atomicOr(flag, 1u);
    }
}

// ---------------- kernel 3: emit (fast path) or exact replay-merge (tie path) ----------------
__global__ void __launch_bounds__(64)
finalize_kernel(char* __restrict__ ws, float* __restrict__ out, int n) {
    const unsigned flag = *(const unsigned*)(ws + WS_FLAG);
    const float* fscore = (const float*)(ws + WS_FSCORE);
    const unsigned short* rank = (const unsigned short*)(ws + WS_RANK);
    const float* sstream = (const float*)(ws + WS_SSCORE);
    const unsigned short* bstream = (const unsigned short*)(ws + WS_SBOX);
    const unsigned short* cntws = (const unsigned short*)(ws + WS_CNT);
    const int lane = threadIdx.x;

    if (flag == 0) {
        // no cross-class frozen-score ties: sort by (score desc, index asc) is exact
        for (int b = lane; b < n; b += 64) {
            int r = rank[b]; float s = fscore[b];
            out[r] = s; out[n + r] = (float)b; out[2 * n + r] = (s > 0.05f) ? 1.f : 0.f;
        }
        return;
    }

    // exact sequential merge of the 80 descending streams, slot-swap tie-break
    __shared__ unsigned short slot_of[NMAX], box_at[NMAX];
    for (int b = lane; b < NMAX; b += 64) { slot_of[b] = (unsigned short)b; box_at[b] = (unsigned short)b; }
    __syncthreads();

    // lane owns class lane (t=0) and class 64+lane (t=1, lanes 0..15)
    int cnt0 = cntws[lane];
    int cnt1 = (lane < NCLS - 64) ? cntws[64 + lane] : 0;
    int p0 = 0, p1 = 0;
    float hs0 = (cnt0 > 0) ? sstream[lane * CAPC] : -1.f;
    int   hb0 = (cnt0 > 0) ? bstream[lane * CAPC] : 0;
    float ns0 = (cnt0 > 1) ? sstream[lane * CAPC + 1] : -1.f;
    int   nb0 = (cnt0 > 1) ? bstream[lane * CAPC + 1] : 0;
    float hs1 = (cnt1 > 0) ? sstream[(64 + lane) * CAPC] : -1.f;
    int   hb1 = (cnt1 > 0) ? bstream[(64 + lane) * CAPC] : 0;
    float ns1 = (cnt1 > 1) ? sstream[(64 + lane) * CAPC + 1] : -1.f;
    int   nb1 = (cnt1 > 1) ? bstream[(64 + lane) * CAPC + 1] : 0;

    for (int i = 0; i < n; i++) {
        float M = fmaxf(hs0, hs1);
        for (int o = 32; o >= 1; o >>= 1) M = fmaxf(M, __shfl_xor(M, o, 64));
        unsigned long long balA = __ballot(hs0 == M);
        unsigned long long balB = __ballot(hs1 == M);
        int wc;
        if (__popcll(balA) + __popcll(balB) == 1) {
            wc = balA ? (__ffsll((unsigned long long)balA) - 1)
                      : (64 + __ffsll((unsigned long long)balB) - 1);
        } else {
            // tie at the max: lowest current slot wins (exact ref semantics)
            unsigned k0 = (hs0 == M) ? (((unsigned)(n - slot_of[hb0]) << 8) | (unsigned)lane) : 0u;
            unsigned k1 = (hs1 == M) ? (((unsigned)(n - slot_of[hb1]) << 8) | (unsigned)(64 + lane)) : 0u;
            unsigned K = k0 > k1 ? k0 : k1;
            for (int o = 32; o >= 1; o >>= 1) {
                unsigned o2 = __shfl_xor(K, o, 64);
                K = K > o2 ? K : o2;
            }
            wc = (int)(K & 0xffu);
        }
        int owner = (wc < 64) ? wc : wc - 64;
        if (lane == owner) {
            int t1 = (wc >= 64);
            int w = t1 ? hb1 : hb0;
            out[i] = M; out[n + i] = (float)w; out[2 * n + i] = (M > 0.05f) ? 1.f : 0.f;
            // swap bookkeeping (only entries future steps can read)
            int j = slot_of[w];
            if (j != i) {
                int d = box_at[i];
                box_at[j] = (unsigned short)d;
                slot_of[d] = (unsigned short)j;
            }
            if (t1) {
                p1++; hs1 = ns1; hb1 = nb1;
                if (p1 + 1 < cnt1) { ns1 = sstream[(64 + lane) * CAPC + p1 + 1]; nb1 = bstream[(64 + lane) * CAPC + p1 + 1]; }
                else ns1 = -1.f;
                if (p1 >= cnt1) hs1 = -1.f;
            } else {
                p0++; hs0 = ns0; hb0 = nb0;
                if (p0 + 1 < cnt0) { ns0 = sstream[lane * CAPC + p0 + 1]; nb0 = bstream[lane * CAPC + p0 + 1]; }
                else ns0 = -1.f;
                if (p0 >= cnt0) hs0 = -1.f;
            }
        }
        __syncthreads();
    }
}

extern "C" void kernel_launch(void* const* d_in, const int* in_sizes, int n_in,
                              void* d_out, int out_size, void* d_ws, size_t ws_size,
                              hipStream_t stream) {
    const float* boxes  = (const float*)d_in[0];  // [N,4] f32
    const float* scores = (const float*)d_in[1];  // [N]   f32
    const int*   idxs   = (const int*)d_in[2];    // [N]   i32
    float* out = (float*)d_out;                   // scores | order | keep (f32)
    char* ws = (char*)d_ws;
    const int n = in_sizes[1];

    max_kernel<<<1, 256, 0, stream>>>(boxes, n * 4, ws);
    nms_class_kernel<<<NCLS, 64, 0, stream>>>(boxes, scores, idxs, ws, n);
    rank_detect_kernel<<<(n + 255) / 256, 256, 0, stream>>>(idxs, ws, n);
    finalize_kernel<<<1, 64, 0, stream>>>(ws, out, n);
}

// Round 4
// 202.041 us; speedup vs baseline: 50.4734x; 9.8005x over previous
//
#include <hip/hip_runtime.h>
#include <math.h>

#define NMAX 3008
#define CAPC 128
#define NCLS 80

// ---- workspace layout (bytes) ----
#define WS_MAXC   0                         // float
#define WS_FLAG   4                         // unsigned
#define WS_FSCORE 16                        // float[NMAX]  frozen score by box
#define WS_ORDER  (WS_FSCORE + 4*NMAX)      // u16[NMAX]    provisional order: rank -> box

// ---------------- kernel 0: global max coord + flag init ----------------
__global__ void max_kernel(const float* __restrict__ boxes, int n4,
                           char* __restrict__ ws) {
    __shared__ float red[256];
    float m = -1e30f;
    for (int i = threadIdx.x; i < n4; i += 256) m = fmaxf(m, boxes[i]);
    red[threadIdx.x] = m;
    __syncthreads();
    for (int s = 128; s > 0; s >>= 1) {
        if (threadIdx.x < s) red[threadIdx.x] = fmaxf(red[threadIdx.x], red[threadIdx.x + s]);
        __syncthreads();
    }
    if (threadIdx.x == 0) {
        *(float*)(ws + WS_MAXC) = red[0];
        *(unsigned*)(ws + WS_FLAG) = 0u;
    }
}

// ---------------- kernel 1: exact f32 per-class soft-NMS sims ----------------
// One wave per class; bit-identical to the global sim's same-class ops
// (cross-class decay is exactly *1.0f). Validated absmax=0 in rounds 2-3.
__global__ void __launch_bounds__(64)
nms_class_kernel(const float* __restrict__ boxes, const float* __restrict__ scores,
                 const int* __restrict__ idxs, char* __restrict__ ws, int n) {
#pragma clang fp contract(off)
    const int c = blockIdx.x;
    const int lane = threadIdx.x;
    const float* maxc_p = (const float*)(ws + WS_MAXC);
    float* fscore = (float*)(ws + WS_FSCORE);

    __shared__ float mx0[CAPC], mx1[CAPC], mx2[CAPC], mx3[CAPC], msc[CAPC];
    __shared__ unsigned short mgid[CAPC];

    const float maxcp1 = maxc_p[0] + 1.0f;
    const float off = (float)c * maxcp1;

    int base = 0;
    for (int k0 = 0; k0 < n; k0 += 64) {
        int k = k0 + lane;
        bool p = (k < n) && (idxs[k] == c);
        unsigned long long m = __ballot(p);
        if (p) {
            int pos = base + __popcll(m & ((1ull << lane) - 1ull));
            if (pos < CAPC) {
                float4 bb = ((const float4*)boxes)[k];
                mx0[pos] = bb.x + off; mx1[pos] = bb.y + off;
                mx2[pos] = bb.z + off; mx3[pos] = bb.w + off;
                msc[pos] = scores[k];
                mgid[pos] = (unsigned short)k;
            }
        }
        base += __popcll(m);
    }
    int cnt = base < CAPC ? base : CAPC;
    __syncthreads();

    float sc0 = -1.f, sc1 = -1.f;
    float a0 = 0, a1 = 0, a2 = 0, a3 = 0, b0 = 0, b1 = 0, b2 = 0, b3 = 0;
    int g0 = 0, g1 = 0;
    if (lane < cnt) {
        sc0 = msc[lane];
        a0 = mx0[lane]; a1 = mx1[lane]; a2 = mx2[lane]; a3 = mx3[lane];
        g0 = mgid[lane];
    }
    if (64 + lane < cnt) {
        sc1 = msc[64 + lane];
        b0 = mx0[64 + lane]; b1 = mx1[64 + lane]; b2 = mx2[64 + lane]; b3 = mx3[64 + lane];
        g1 = mgid[64 + lane];
    }

    for (int s = 0; s < cnt; s++) {
        float M = fmaxf(sc0, sc1);
        for (int o = 32; o >= 1; o >>= 1) M = fmaxf(M, __shfl_xor(M, o, 64));
        unsigned long long balA = __ballot(sc0 == M);
        int wm;
        if (balA) wm = __ffsll((unsigned long long)balA) - 1;
        else {
            unsigned long long balB = __ballot(sc1 == M);
            wm = 64 + __ffsll((unsigned long long)balB) - 1;
        }
        float w0 = mx0[wm], w1 = mx1[wm], w2 = mx2[wm], w3 = mx3[wm];
        if (wm == lane)            { fscore[g0] = M; sc0 = -1.f; }
        else if (wm == 64 + lane)  { fscore[g1] = M; sc1 = -1.f; }
        float area_w = (w2 - w0) * (w3 - w1);
        if (sc0 >= 0.f) {
            float x1 = fmaxf(w0, a0), y1 = fmaxf(w1, a1);
            float x2 = fminf(w2, a2), y2 = fminf(w3, a3);
            float iw = fmaxf(x2 - x1, 0.f), ih = fmaxf(y2 - y1, 0.f);
            float inter = iw * ih;
            float area_b = (a2 - a0) * (a3 - a1);
            float iou = inter / ((area_w + area_b) - inter);
            float arg = -(iou * iou) / 0.5f;
            sc0 = sc0 * (float)exp((double)arg);
        }
        if (sc1 >= 0.f) {
            float x1 = fmaxf(w0, b0), y1 = fmaxf(w1, b1);
            float x2 = fminf(w2, b2), y2 = fminf(w3, b3);
            float iw = fmaxf(x2 - x1, 0.f), ih = fmaxf(y2 - y1, 0.f);
            float inter = iw * ih;
            float area_b = (b2 - b0) * (b3 - b1);
            float iou = inter / ((area_w + area_b) - inter);
            float arg = -(iou * iou) / 0.5f;
            sc1 = sc1 * (float)exp((double)arg);
        }
    }
}

// ---------------- kernel 2: provisional order + unsafe-tie flag ----------------
// rank = (#greater) + (#equal with lower index). Flag set only if a tie group
// has a member with index < group_end (i.e. some member may have been
// displaced before emission -> slot order may differ from index order).
__global__ void __launch_bounds__(256)
rank_kernel(char* __restrict__ ws, int n) {
    __shared__ float sv[NMAX];
    const float* fscore = (const float*)(ws + WS_FSCORE);
    unsigned short* ordp = (unsigned short*)(ws + WS_ORDER);
    unsigned* flag = (unsigned*)(ws + WS_FLAG);
    const int tid = threadIdx.x;
    for (int j = tid; j < n; j += 256) sv[j] = fscore[j];
    __syncthreads();
    int i = blockIdx.x * 256 + tid;
    if (i < n) {
        float s = sv[i];
        int gt = 0, eq = 0, eqlt = 0;
        for (int j = 0; j < n; j++) {
            float x = sv[j];
            gt   += (x > s) ? 1 : 0;
            eq   += (x == s) ? 1 : 0;            // includes self
            eqlt += (x == s && j < i) ? 1 : 0;
        }
        ordp[gt + eqlt] = (unsigned short)i;
        if (eq >= 2 && i < gt + eq) atomicOr(flag, 1u);
    }
}

// ---------------- kernel 3: tie fix-up walk + emit ----------------
// If flag: lane 0 replays the slot-swap bookkeeping (1 read-chain + 2 writes
// per step) up to the end of the LAST tie group, resolving each tie group by
// iteratively picking the member with the lowest current slot (exact ref
// tie-break; tied boxes provably don't decay each other, so scores are
// unaffected by the within-group order).
__global__ void __launch_bounds__(64)
finalize_kernel(char* __restrict__ ws, float* __restrict__ out, int n) {
    __shared__ unsigned short ordL[NMAX];   // rank -> box (corrected in-place)
    __shared__ float          svL[NMAX];    // rank -> score
    __shared__ unsigned short slotL[NMAX];  // box  -> current slot
    __shared__ unsigned short batL[NMAX];   // slot -> box
    __shared__ unsigned char  tieL[NMAX];   // rank r ties with r+1
    __shared__ int rstop_s;

    const float* fscore = (const float*)(ws + WS_FSCORE);
    const unsigned short* ordp = (const unsigned short*)(ws + WS_ORDER);
    const unsigned flag = *(const unsigned*)(ws + WS_FLAG);
    const int lane = threadIdx.x;

    for (int r = lane; r < n; r += 64) {
        unsigned short b = ordp[r];
        ordL[r] = b;
        svL[r] = fscore[b];
        slotL[r] = (unsigned short)r;   // r used as box id here
        batL[r]  = (unsigned short)r;
    }
    __syncthreads();
    int rmax = -1;
    for (int r = lane; r < n; r += 64) {
        unsigned char t = (r + 1 < n) && (svL[r] == svL[r + 1]);
        tieL[r] = t;
        if (t) rmax = r;
    }
    // wave-reduce max tie position -> walk stop point (end of last tie group)
    for (int o = 32; o >= 1; o >>= 1) rmax = max(rmax, __shfl_xor(rmax, o, 64));
    if (lane == 0) rstop_s = rmax + 2;   // last group ends at rmax+1 inclusive
    __syncthreads();

    if (flag && lane == 0) {
        const int rstop = rstop_s;
        int r = 0;
        while (r < rstop) {
            if (!tieL[r]) {
                int w = ordL[r];
                int j = slotL[w];
                int d = batL[r];
                batL[j] = (unsigned short)d;
                slotL[d] = (unsigned short)j;
                r++;
            } else {
                int g = 1;
                while (tieL[r + g - 1]) g++;
                for (int t = 0; t < g; t++) {
                    int bi = r + t;
                    int bs = slotL[ordL[bi]];
                    for (int q = r + t + 1; q < r + g; q++) {
                        int s2 = slotL[ordL[q]];
                        if (s2 < bs) { bs = s2; bi = q; }
                    }
                    unsigned short w = ordL[bi];
                    ordL[bi] = ordL[r + t];
                    ordL[r + t] = w;
                    int d = batL[r + t];
                    batL[bs] = (unsigned short)d;
                    slotL[d] = (unsigned short)bs;
                }
                r += g;
            }
        }
    }
    __syncthreads();

    for (int r = lane; r < n; r += 64) {
        float s = svL[r];
        out[r] = s;
        out[n + r] = (float)ordL[r];
        out[2 * n + r] = (s > 0.05f) ? 1.f : 0.f;
    }
}

extern "C" void kernel_launch(void* const* d_in, const int* in_sizes, int n_in,
                              void* d_out, int out_size, void* d_ws, size_t ws_size,
                              hipStream_t stream) {
    const float* boxes  = (const float*)d_in[0];  // [N,4] f32
    const float* scores = (const float*)d_in[1];  // [N]   f32
    const int*   idxs   = (const int*)d_in[2];    // [N]   i32
    float* out = (float*)d_out;                   // scores | order | keep (f32)
    char* ws = (char*)d_ws;
    const int n = in_sizes[1];

    max_kernel<<<1, 256, 0, stream>>>(boxes, n * 4, ws);
    nms_class_kernel<<<NCLS, 64, 0, stream>>>(boxes, scores, idxs, ws, n);
    rank_kernel<<<(n + 255) / 256, 256, 0, stream>>>(ws, n);
    finalize_kernel<<<1, 64, 0, stream>>>(ws, out, n);
}

// Round 5
// 132.866 us; speedup vs baseline: 76.7519x; 1.5206x over previous
//
#include <hip/hip_runtime.h>
#include <math.h>

#define NMAX 3008
#define CAPC 128
#define NCLS 80
#define JC   8                 // j-chunks for the rank scan
#define JCH  ((NMAX + JC - 1) / JC)

// ---- workspace layout (bytes) ----
#define WS_MAXC   0                         // float
#define WS_FSCORE 16                        // float[NMAX]  frozen score by box
#define WS_GT     (WS_FSCORE + 4*NMAX)      // u32[NMAX]    #scores strictly greater
#define WS_EQLT   (WS_GT + 4*NMAX)          // u32[NMAX]    #equal with lower index
#define WS_EQ     (WS_EQLT + 4*NMAX)        // u32[NMAX]    #equal (incl self)

// ---------------- kernel 0: global max coord + counter zero-init ----------------
__global__ void max_kernel(const float* __restrict__ boxes, int n4,
                           char* __restrict__ ws) {
    __shared__ float red[256];
    unsigned* ctr = (unsigned*)(ws + WS_GT);
    for (int i = threadIdx.x; i < 3 * NMAX; i += 256) ctr[i] = 0u;
    float m = -1e30f;
    for (int i = threadIdx.x; i < n4; i += 256) m = fmaxf(m, boxes[i]);
    red[threadIdx.x] = m;
    __syncthreads();
    for (int s = 128; s > 0; s >>= 1) {
        if (threadIdx.x < s) red[threadIdx.x] = fmaxf(red[threadIdx.x], red[threadIdx.x + s]);
        __syncthreads();
    }
    if (threadIdx.x == 0) *(float*)(ws + WS_MAXC) = red[0];
}

// ---------------- kernel 1: exact f32 per-class soft-NMS sims ----------------
// One wave per class; bit-identical to the global sim's same-class ops
// (cross-class decay is exactly *1.0f). Validated absmax=0 in rounds 2-4.
__global__ void __launch_bounds__(64)
nms_class_kernel(const float* __restrict__ boxes, const float* __restrict__ scores,
                 const int* __restrict__ idxs, char* __restrict__ ws, int n) {
#pragma clang fp contract(off)
    const int c = blockIdx.x;
    const int lane = threadIdx.x;
    const float* maxc_p = (const float*)(ws + WS_MAXC);
    float* fscore = (float*)(ws + WS_FSCORE);

    __shared__ float mx0[CAPC], mx1[CAPC], mx2[CAPC], mx3[CAPC], msc[CAPC];
    __shared__ unsigned short mgid[CAPC];

    const float maxcp1 = maxc_p[0] + 1.0f;
    const float off = (float)c * maxcp1;

    int base = 0;
    for (int k0 = 0; k0 < n; k0 += 64) {
        int k = k0 + lane;
        bool p = (k < n) && (idxs[k] == c);
        unsigned long long m = __ballot(p);
        if (p) {
            int pos = base + __popcll(m & ((1ull << lane) - 1ull));
            if (pos < CAPC) {
                float4 bb = ((const float4*)boxes)[k];
                mx0[pos] = bb.x + off; mx1[pos] = bb.y + off;
                mx2[pos] = bb.z + off; mx3[pos] = bb.w + off;
                msc[pos] = scores[k];
                mgid[pos] = (unsigned short)k;
            }
        }
        base += __popcll(m);
    }
    int cnt = base < CAPC ? base : CAPC;
    __syncthreads();

    float sc0 = -1.f, sc1 = -1.f;
    float a0 = 0, a1 = 0, a2 = 0, a3 = 0, b0 = 0, b1 = 0, b2 = 0, b3 = 0;
    int g0 = 0, g1 = 0;
    if (lane < cnt) {
        sc0 = msc[lane];
        a0 = mx0[lane]; a1 = mx1[lane]; a2 = mx2[lane]; a3 = mx3[lane];
        g0 = mgid[lane];
    }
    if (64 + lane < cnt) {
        sc1 = msc[64 + lane];
        b0 = mx0[64 + lane]; b1 = mx1[64 + lane]; b2 = mx2[64 + lane]; b3 = mx3[64 + lane];
        g1 = mgid[64 + lane];
    }

    for (int s = 0; s < cnt; s++) {
        float M = fmaxf(sc0, sc1);
        for (int o = 32; o >= 1; o >>= 1) M = fmaxf(M, __shfl_xor(M, o, 64));
        unsigned long long balA = __ballot(sc0 == M);
        int wm;
        if (balA) wm = __ffsll((unsigned long long)balA) - 1;
        else {
            unsigned long long balB = __ballot(sc1 == M);
            wm = 64 + __ffsll((unsigned long long)balB) - 1;
        }
        float w0 = mx0[wm], w1 = mx1[wm], w2 = mx2[wm], w3 = mx3[wm];
        if (wm == lane)            { fscore[g0] = M; sc0 = -1.f; }
        else if (wm == 64 + lane)  { fscore[g1] = M; sc1 = -1.f; }
        float area_w = (w2 - w0) * (w3 - w1);
        if (sc0 >= 0.f) {
            float x1 = fmaxf(w0, a0), y1 = fmaxf(w1, a1);
            float x2 = fminf(w2, a2), y2 = fminf(w3, a3);
            float iw = fmaxf(x2 - x1, 0.f), ih = fmaxf(y2 - y1, 0.f);
            float inter = iw * ih;
            float area_b = (a2 - a0) * (a3 - a1);
            float iou = inter / ((area_w + area_b) - inter);
            float arg = -(iou * iou) / 0.5f;
            sc0 = sc0 * (float)exp((double)arg);
        }
        if (sc1 >= 0.f) {
            float x1 = fmaxf(w0, b0), y1 = fmaxf(w1, b1);
            float x2 = fminf(w2, b2), y2 = fminf(w3, b3);
            float iw = fmaxf(x2 - x1, 0.f), ih = fmaxf(y2 - y1, 0.f);
            float inter = iw * ih;
            float area_b = (b2 - b0) * (b3 - b1);
            float iou = inter / ((area_w + area_b) - inter);
            float arg = -(iou * iou) / 0.5f;
            sc1 = sc1 * (float)exp((double)arg);
        }
    }
}

// ---------------- kernel 2: partial rank counts (j-split) ----------------
// Block (bx, by): i = bx*256+tx, j-chunk by. Accumulate (gt, eqlt, eq)
// over the chunk, one atomicAdd triple per i. Integer atomics -> deterministic.
__global__ void __launch_bounds__(256)
partial_rank_kernel(char* __restrict__ ws, int n) {
    __shared__ float sv[JCH];
    const float* fscore = (const float*)(ws + WS_FSCORE);
    unsigned* GT   = (unsigned*)(ws + WS_GT);
    unsigned* EQLT = (unsigned*)(ws + WS_EQLT);
    unsigned* EQ   = (unsigned*)(ws + WS_EQ);

    const int chunk = (n + JC - 1) / JC;
    const int j0 = blockIdx.y * chunk;
    const int jn = min(n - j0, chunk);
    for (int j = threadIdx.x; j < jn; j += 256) sv[j] = fscore[j0 + j];
    __syncthreads();

    int i = blockIdx.x * 256 + threadIdx.x;
    if (i < n) {
        float s = fscore[i];
        int gt = 0, eq = 0, eqlt = 0;
        for (int jj = 0; jj < jn; jj++) {
            float x = sv[jj];
            gt   += (x > s) ? 1 : 0;
            eq   += (x == s) ? 1 : 0;
            eqlt += (x == s && (j0 + jj) < i) ? 1 : 0;
        }
        atomicAdd(GT + i,   (unsigned)gt);
        atomicAdd(EQLT + i, (unsigned)eqlt);
        atomicAdd(EQ + i,   (unsigned)eq);
    }
}

// ---------------- kernel 3: scatter + tie fix-up walk + emit ----------------
__global__ void __launch_bounds__(64)
finalize_kernel(char* __restrict__ ws, float* __restrict__ out, int n) {
    __shared__ unsigned short ordL[NMAX];   // rank -> box (corrected in-place)
    __shared__ float          svL[NMAX];    // rank -> score
    __shared__ unsigned short slotL[NMAX];  // box  -> current slot
    __shared__ unsigned short batL[NMAX];   // slot -> box
    __shared__ unsigned char  tieL[NMAX];   // rank r ties with r+1
    __shared__ int rstop_s;

    const float* fscore = (const float*)(ws + WS_FSCORE);
    const unsigned* GT   = (const unsigned*)(ws + WS_GT);
    const unsigned* EQLT = (const unsigned*)(ws + WS_EQLT);
    const unsigned* EQ   = (const unsigned*)(ws + WS_EQ);
    const int lane = threadIdx.x;

    int myflag = 0;
    for (int b = lane; b < n; b += 64) {
        unsigned gt = GT[b], eqlt = EQLT[b], eq = EQ[b];
        int r = (int)(gt + eqlt);
        ordL[r] = (unsigned short)b;
        svL[r] = fscore[b];
        slotL[b] = (unsigned short)b;
        batL[b]  = (unsigned short)b;
        // unsafe only if this tie group has a member displaced before emission
        myflag |= (eq >= 2 && (unsigned)b < gt + eq) ? 1 : 0;
    }
    const int flag = (__ballot(myflag) != 0ull);
    __syncthreads();

    int rmax = -1;
    for (int r = lane; r < n; r += 64) {
        unsigned char t = (r + 1 < n) && (svL[r] == svL[r + 1]);
        tieL[r] = t;
        if (t) rmax = r;
    }
    for (int o = 32; o >= 1; o >>= 1) rmax = max(rmax, __shfl_xor(rmax, o, 64));
    if (lane == 0) rstop_s = rmax + 2;
    __syncthreads();

    if (flag && lane == 0) {
        const int rstop = rstop_s;
        int r = 0;
        while (r < rstop) {
            if (!tieL[r]) {
                int w = ordL[r];
                int j = slotL[w];
                int d = batL[r];
                batL[j] = (unsigned short)d;
                slotL[d] = (unsigned short)j;
                r++;
            } else {
                int g = 1;
                while (tieL[r + g - 1]) g++;
                for (int t = 0; t < g; t++) {
                    int bi = r + t;
                    int bs = slotL[ordL[bi]];
                    for (int q = r + t + 1; q < r + g; q++) {
                        int s2 = slotL[ordL[q]];
                        if (s2 < bs) { bs = s2; bi = q; }
                    }
                    unsigned short w = ordL[bi];
                    ordL[bi] = ordL[r + t];
                    ordL[r + t] = w;
                    int d = batL[r + t];
                    batL[bs] = (unsigned short)d;
                    slotL[d] = (unsigned short)bs;
                }
                r += g;
            }
        }
    }
    __syncthreads();

    for (int r = lane; r < n; r += 64) {
        float s = svL[r];
        out[r] = s;
        out[n + r] = (float)ordL[r];
        out[2 * n + r] = (s > 0.05f) ? 1.f : 0.f;
    }
}

extern "C" void kernel_launch(void* const* d_in, const int* in_sizes, int n_in,
                              void* d_out, int out_size, void* d_ws, size_t ws_size,
                              hipStream_t stream) {
    const float* boxes  = (const float*)d_in[0];  // [N,4] f32
    const float* scores = (const float*)d_in[1];  // [N]   f32
    const int*   idxs   = (const int*)d_in[2];    // [N]   i32
    float* out = (float*)d_out;                   // scores | order | keep (f32)
    char* ws = (char*)d_ws;
    const int n = in_sizes[1];

    max_kernel<<<1, 256, 0, stream>>>(boxes, n * 4, ws);
    nms_class_kernel<<<NCLS, 64, 0, stream>>>(boxes, scores, idxs, ws, n);
    dim3 rgrid((n + 255) / 256, JC);
    partial_rank_kernel<<<rgrid, 256, 0, stream>>>(ws, n);
    finalize_kernel<<<1, 64, 0, stream>>>(ws, out, n);
}

// Round 6
// 130.360 us; speedup vs baseline: 78.2271x; 1.0192x over previous
//
#include <hip/hip_runtime.h>
#include <math.h>

#define NMAX 3008
#define CAPC 128      // member compaction capacity
#define DCAP 96       // decay-matrix row capacity
#define DSTR 128      // decay-matrix row stride (128+lane always in-bounds)
#define NCLS 80
#define JC   16       // j-chunks for the rank scan
#define JCH  ((NMAX + JC - 1) / JC)

// ---- workspace layout (bytes) ----
#define WS_MAXC   0                         // float
#define WS_FSCORE 16                        // float[NMAX]  frozen score by box
#define WS_GT     (WS_FSCORE + 4*NMAX)      // u32[NMAX]    #scores strictly greater
#define WS_EQLT   (WS_GT + 4*NMAX)          // u32[NMAX]    #equal with lower index
#define WS_EQ     (WS_EQLT + 4*NMAX)        // u32[NMAX]    #equal (incl self)

// ---------------- kernel 0: global max coord + counter zero-init ----------------
__global__ void max_kernel(const float* __restrict__ boxes, int n4,
                           char* __restrict__ ws) {
    __shared__ float red[256];
    unsigned* ctr = (unsigned*)(ws + WS_GT);
    for (int i = threadIdx.x; i < 3 * NMAX; i += 256) ctr[i] = 0u;
    float m = -1e30f;
    for (int i = threadIdx.x; i < n4; i += 256) m = fmaxf(m, boxes[i]);
    red[threadIdx.x] = m;
    __syncthreads();
    for (int s = 128; s > 0; s >>= 1) {
        if (threadIdx.x < s) red[threadIdx.x] = fmaxf(red[threadIdx.x], red[threadIdx.x + s]);
        __syncthreads();
    }
    if (threadIdx.x == 0) *(float*)(ws + WS_MAXC) = red[0];
}

// ---------------- kernel 1: exact f32 per-class soft-NMS sims ----------------
// One wave per class. Decay factors D[i][j] are pure functions of immutable
// box pairs -> precomputed in parallel (exp latency overlapped across
// independent rows; inter==0 pairs give decay==1.0f exactly, exp skipped).
// The serial loop then multiplies the SAME factor values in the SAME order as
// the validated in-loop version -> bit-identical scores.
__global__ void __launch_bounds__(64)
nms_class_kernel(const float* __restrict__ boxes, const float* __restrict__ scores,
                 const int* __restrict__ idxs, char* __restrict__ ws, int n) {
#pragma clang fp contract(off)
    const int c = blockIdx.x;
    const int lane = threadIdx.x;
    const float* maxc_p = (const float*)(ws + WS_MAXC);
    float* fscore = (float*)(ws + WS_FSCORE);

    __shared__ float mx0[CAPC], mx1[CAPC], mx2[CAPC], mx3[CAPC], msc[CAPC];
    __shared__ unsigned short mgid[CAPC];
    __shared__ float D[DCAP * DSTR];

    const float maxcp1 = maxc_p[0] + 1.0f;
    const float off = (float)c * maxcp1;

    // compact this class's members (index-ordered) into LDS
    int base = 0;
    for (int k0 = 0; k0 < n; k0 += 64) {
        int k = k0 + lane;
        bool p = (k < n) && (idxs[k] == c);
        unsigned long long m = __ballot(p);
        if (p) {
            int pos = base + __popcll(m & ((1ull << lane) - 1ull));
            if (pos < CAPC) {
                float4 bb = ((const float4*)boxes)[k];
                mx0[pos] = bb.x + off; mx1[pos] = bb.y + off;
                mx2[pos] = bb.z + off; mx3[pos] = bb.w + off;
                msc[pos] = scores[k];
                mgid[pos] = (unsigned short)k;
            }
        }
        base += __popcll(m);
    }
    int cnt = base < CAPC ? base : CAPC;
    __syncthreads();

    if (cnt <= DCAP) {
        // ---- precompute decay matrix: row i = winner i, col j = target j ----
        const bool v0 = lane < cnt, v1 = 64 + lane < cnt;
        float c00 = 0, c01 = 0, c02 = 0, c03 = 0;
        float c10 = 0, c11 = 0, c12 = 0, c13 = 0;
        if (v0) { c00 = mx0[lane]; c01 = mx1[lane]; c02 = mx2[lane]; c03 = mx3[lane]; }
        if (v1) { c10 = mx0[64 + lane]; c11 = mx1[64 + lane]; c12 = mx2[64 + lane]; c13 = mx3[64 + lane]; }
        const float ab0 = (c02 - c00) * (c03 - c01);
        const float ab1 = (c12 - c10) * (c13 - c11);
        for (int i = 0; i < cnt; i++) {
            float w0 = mx0[i], w1 = mx1[i], w2 = mx2[i], w3 = mx3[i];
            float aw = (w2 - w0) * (w3 - w1);
            if (v0) {
                float x1 = fmaxf(w0, c00), y1 = fmaxf(w1, c01);
                float x2 = fminf(w2, c02), y2 = fminf(w3, c03);
                float iw = fmaxf(x2 - x1, 0.f), ih = fmaxf(y2 - y1, 0.f);
                float inter = iw * ih;
                float d = 1.0f;                 // exp(-0.0) == 1.0f exactly
                if (inter != 0.f) {
                    float iou = inter / ((aw + ab0) - inter);
                    float arg = -(iou * iou) / 0.5f;
                    d = (float)exp((double)arg);
                }
                D[i * DSTR + lane] = d;
            }
            if (v1) {
                float x1 = fmaxf(w0, c10), y1 = fmaxf(w1, c11);
                float x2 = fminf(w2, c12), y2 = fminf(w3, c13);
                float iw = fmaxf(x2 - x1, 0.f), ih = fmaxf(y2 - y1, 0.f);
                float inter = iw * ih;
                float d = 1.0f;
                if (inter != 0.f) {
                    float iou = inter / ((aw + ab1) - inter);
                    float arg = -(iou * iou) / 0.5f;
                    d = (float)exp((double)arg);
                }
                D[i * DSTR + 64 + lane] = d;
            }
        }
        __syncthreads();

        // ---- serial selection loop: argmax + row multiply only ----
        float sc0 = v0 ? msc[lane] : -1.f;
        float sc1 = v1 ? msc[64 + lane] : -1.f;
        int g0 = v0 ? mgid[lane] : 0;
        int g1 = v1 ? mgid[64 + lane] : 0;

        for (int s = 0; s < cnt; s++) {
            float M = fmaxf(sc0, sc1);
            for (int o = 32; o >= 1; o >>= 1) M = fmaxf(M, __shfl_xor(M, o, 64));
            unsigned long long balA = __ballot(sc0 == M);
            int wm;
            if (balA) wm = __ffsll(balA) - 1;
            else      wm = 64 + __ffsll(__ballot(sc1 == M)) - 1;
            const float* Drow = &D[wm * DSTR];
            float d0 = Drow[lane];
            float d1 = Drow[64 + lane];
            if (wm == lane)           { fscore[g0] = M; sc0 = -1.f; }
            else if (wm == 64 + lane) { fscore[g1] = M; sc1 = -1.f; }
            if (sc0 >= 0.f) sc0 = sc0 * d0;
            if (sc1 >= 0.f) sc1 = sc1 * d1;
        }
    } else {
        // ---- fallback (cnt > DCAP): validated in-loop decay path ----
        float sc0 = -1.f, sc1 = -1.f;
        float a0 = 0, a1 = 0, a2 = 0, a3 = 0, b0 = 0, b1 = 0, b2 = 0, b3 = 0;
        int g0 = 0, g1 = 0;
        if (lane < cnt) {
            sc0 = msc[lane];
            a0 = mx0[lane]; a1 = mx1[lane]; a2 = mx2[lane]; a3 = mx3[lane];
            g0 = mgid[lane];
        }
        if (64 + lane < cnt) {
            sc1 = msc[64 + lane];
            b0 = mx0[64 + lane]; b1 = mx1[64 + lane]; b2 = mx2[64 + lane]; b3 = mx3[64 + lane];
            g1 = mgid[64 + lane];
        }
        for (int s = 0; s < cnt; s++) {
            float M = fmaxf(sc0, sc1);
            for (int o = 32; o >= 1; o >>= 1) M = fmaxf(M, __shfl_xor(M, o, 64));
            unsigned long long balA = __ballot(sc0 == M);
            int wm;
            if (balA) wm = __ffsll(balA) - 1;
            else      wm = 64 + __ffsll(__ballot(sc1 == M)) - 1;
            float w0 = mx0[wm], w1 = mx1[wm], w2 = mx2[wm], w3 = mx3[wm];
            if (wm == lane)           { fscore[g0] = M; sc0 = -1.f; }
            else if (wm == 64 + lane) { fscore[g1] = M; sc1 = -1.f; }
            float area_w = (w2 - w0) * (w3 - w1);
            if (sc0 >= 0.f) {
                float x1 = fmaxf(w0, a0), y1 = fmaxf(w1, a1);
                float x2 = fminf(w2, a2), y2 = fminf(w3, a3);
                float iw = fmaxf(x2 - x1, 0.f), ih = fmaxf(y2 - y1, 0.f);
                float inter = iw * ih;
                float area_b = (a2 - a0) * (a3 - a1);
                float iou = inter / ((area_w + area_b) - inter);
                float arg = -(iou * iou) / 0.5f;
                sc0 = sc0 * (float)exp((double)arg);
            }
            if (sc1 >= 0.f) {
                float x1 = fmaxf(w0, b0), y1 = fmaxf(w1, b1);
                float x2 = fminf(w2, b2), y2 = fminf(w3, b3);
                float iw = fmaxf(x2 - x1, 0.f), ih = fmaxf(y2 - y1, 0.f);
                float inter = iw * ih;
                float area_b = (b2 - b0) * (b3 - b1);
                float iou = inter / ((area_w + area_b) - inter);
                float arg = -(iou * iou) / 0.5f;
                sc1 = sc1 * (float)exp((double)arg);
            }
        }
    }
}

// ---------------- kernel 2: partial rank counts (j-split) ----------------
__global__ void __launch_bounds__(256)
partial_rank_kernel(char* __restrict__ ws, int n) {
    __shared__ float sv[JCH];
    const float* fscore = (const float*)(ws + WS_FSCORE);
    unsigned* GT   = (unsigned*)(ws + WS_GT);
    unsigned* EQLT = (unsigned*)(ws + WS_EQLT);
    unsigned* EQ   = (unsigned*)(ws + WS_EQ);

    const int chunk = (n + JC - 1) / JC;
    const int j0 = blockIdx.y * chunk;
    const int jn = min(n - j0, chunk);
    for (int j = threadIdx.x; j < jn; j += 256) sv[j] = fscore[j0 + j];
    __syncthreads();

    int i = blockIdx.x * 256 + threadIdx.x;
    if (i < n) {
        float s = fscore[i];
        int gt = 0, eq = 0, eqlt = 0;
        for (int jj = 0; jj < jn; jj++) {
            float x = sv[jj];
            gt   += (x > s) ? 1 : 0;
            eq   += (x == s) ? 1 : 0;
            eqlt += (x == s && (j0 + jj) < i) ? 1 : 0;
        }
        atomicAdd(GT + i,   (unsigned)gt);
        atomicAdd(EQLT + i, (unsigned)eqlt);
        atomicAdd(EQ + i,   (unsigned)eq);
    }
}

// ---------------- kernel 3: scatter + tie fix-up walk + emit ----------------
__global__ void __launch_bounds__(64)
finalize_kernel(char* __restrict__ ws, float* __restrict__ out, int n) {
    __shared__ unsigned short ordL[NMAX];   // rank -> box (corrected in-place)
    __shared__ float          svL[NMAX];    // rank -> score
    __shared__ unsigned short slotL[NMAX];  // box  -> current slot
    __shared__ unsigned short batL[NMAX];   // slot -> box
    __shared__ unsigned char  tieL[NMAX];   // rank r ties with r+1
    __shared__ int rstop_s;

    const float* fscore = (const float*)(ws + WS_FSCORE);
    const unsigned* GT   = (const unsigned*)(ws + WS_GT);
    const unsigned* EQLT = (const unsigned*)(ws + WS_EQLT);
    const unsigned* EQ   = (const unsigned*)(ws + WS_EQ);
    const int lane = threadIdx.x;

    int myflag = 0;
    for (int b = lane; b < n; b += 64) {
        unsigned gt = GT[b], eqlt = EQLT[b], eq = EQ[b];
        int r = (int)(gt + eqlt);
        ordL[r] = (unsigned short)b;
        svL[r] = fscore[b];
        slotL[b] = (unsigned short)b;
        batL[b]  = (unsigned short)b;
        myflag |= (eq >= 2 && (unsigned)b < gt + eq) ? 1 : 0;
    }
    const int flag = (__ballot(myflag) != 0ull);
    __syncthreads();

    int rmax = -1;
    for (int r = lane; r < n; r += 64) {
        unsigned char t = (r + 1 < n) && (svL[r] == svL[r + 1]);
        tieL[r] = t;
        if (t) rmax = r;
    }
    for (int o = 32; o >= 1; o >>= 1) rmax = max(rmax, __shfl_xor(rmax, o, 64));
    if (lane == 0) rstop_s = rmax + 2;
    __syncthreads();

    if (flag && lane == 0) {
        const int rstop = rstop_s;
        int r = 0;
        while (r < rstop) {
            if (!tieL[r]) {
                int w = ordL[r];
                int j = slotL[w];
                int d = batL[r];
                batL[j] = (unsigned short)d;
                slotL[d] = (unsigned short)j;
                r++;
            } else {
                int g = 1;
                while (tieL[r + g - 1]) g++;
                for (int t = 0; t < g; t++) {
                    int bi = r + t;
                    int bs = slotL[ordL[bi]];
                    for (int q = r + t + 1; q < r + g; q++) {
                        int s2 = slotL[ordL[q]];
                        if (s2 < bs) { bs = s2; bi = q; }
                    }
                    unsigned short w = ordL[bi];
                    ordL[bi] = ordL[r + t];
                    ordL[r + t] = w;
                    int d = batL[r + t];
                    batL[bs] = (unsigned short)d;
                    slotL[d] = (unsigned short)bs;
                }
                r += g;
            }
        }
    }
    __syncthreads();

    for (int r = lane; r < n; r += 64) {
        float s = svL[r];
        out[r] = s;
        out[n + r] = (float)ordL[r];
        out[2 * n + r] = (s > 0.05f) ? 1.f : 0.f;
    }
}

extern "C" void kernel_launch(void* const* d_in, const int* in_sizes, int n_in,
                              void* d_out, int out_size, void* d_ws, size_t ws_size,
                              hipStream_t stream) {
    const float* boxes  = (const float*)d_in[0];  // [N,4] f32
    const float* scores = (const float*)d_in[1];  // [N]   f32
    const int*   idxs   = (const int*)d_in[2];    // [N]   i32
    float* out = (float*)d_out;                   // scores | order | keep (f32)
    char* ws = (char*)d_ws;
    const int n = in_sizes[1];

    max_kernel<<<1, 256, 0, stream>>>(boxes, n * 4, ws);
    nms_class_kernel<<<NCLS, 64, 0, stream>>>(boxes, scores, idxs, ws, n);
    dim3 rgrid((n + 255) / 256, JC);
    partial_rank_kernel<<<rgrid, 256, 0, stream>>>(ws, n);
    finalize_kernel<<<1, 64, 0, stream>>>(ws, out, n);
}

// Round 7
// 115.507 us; speedup vs baseline: 88.2860x; 1.1286x over previous
//
#include <hip/hip_runtime.h>
#include <math.h>

#define NMAX 3008
#define NCHK 47       // ceil(NMAX/64) idx chunks
#define CAPC 128      // member compaction capacity
#define DCAP 96       // decay-matrix row capacity (2-slot fallback)
#define DSTR 128
#define NCLS 80
#define JC   16       // j-chunks for the rank scan
#define JCH  ((NMAX + JC - 1) / JC)

// ---- workspace layout (bytes) ----
#define WS_MAXC   0                         // float
#define WS_FSCORE 16                        // float[NMAX]  frozen score by box
#define WS_GT     (WS_FSCORE + 4*NMAX)      // u32[NMAX]
#define WS_EQLT   (WS_GT + 4*NMAX)          // u32[NMAX]
#define WS_EQ     (WS_EQLT + 4*NMAX)        // u32[NMAX]

// full-wave (64) max via DPP: row prefix-max then cross-row bcast; result in
// lane 63, readlane-broadcast. VALU-latency chain (~8 cyc/stage) vs DS-domain
// __shfl_xor (~120 cyc/stage).
__device__ __forceinline__ float wave_max64(float x) {
    int v;
    v = __float_as_int(x);
    x = fmaxf(x, __int_as_float(__builtin_amdgcn_update_dpp(v, v, 0x111, 0xf, 0xf, false)));
    v = __float_as_int(x);
    x = fmaxf(x, __int_as_float(__builtin_amdgcn_update_dpp(v, v, 0x112, 0xf, 0xf, false)));
    v = __float_as_int(x);
    x = fmaxf(x, __int_as_float(__builtin_amdgcn_update_dpp(v, v, 0x114, 0xf, 0xf, false)));
    v = __float_as_int(x);
    x = fmaxf(x, __int_as_float(__builtin_amdgcn_update_dpp(v, v, 0x118, 0xf, 0xf, false)));
    v = __float_as_int(x);
    x = fmaxf(x, __int_as_float(__builtin_amdgcn_update_dpp(v, v, 0x142, 0xa, 0xf, false)));
    v = __float_as_int(x);
    x = fmaxf(x, __int_as_float(__builtin_amdgcn_update_dpp(v, v, 0x143, 0xc, 0xf, false)));
    return __int_as_float(__builtin_amdgcn_readlane(__float_as_int(x), 63));
}

// ---------------- kernel 0: global max coord + counter zero-init ----------------
__global__ void max_kernel(const float* __restrict__ boxes, int n4,
                           char* __restrict__ ws) {
    __shared__ float red[256];
    unsigned* ctr = (unsigned*)(ws + WS_GT);
    for (int i = threadIdx.x; i < 3 * NMAX; i += 256) ctr[i] = 0u;
    float m = -1e30f;
    for (int i = threadIdx.x; i < n4; i += 256) m = fmaxf(m, boxes[i]);
    red[threadIdx.x] = m;
    __syncthreads();
    for (int s = 128; s > 0; s >>= 1) {
        if (threadIdx.x < s) red[threadIdx.x] = fmaxf(red[threadIdx.x], red[threadIdx.x + s]);
        __syncthreads();
    }
    if (threadIdx.x == 0) *(float*)(ws + WS_MAXC) = red[0];
}

// ---------------- kernel 1: exact f32 per-class soft-NMS sims ----------------
__global__ void __launch_bounds__(64)
nms_class_kernel(const float* __restrict__ boxes, const float* __restrict__ scores,
                 const int* __restrict__ idxs, char* __restrict__ ws, int n) {
#pragma clang fp contract(off)
    const int c = blockIdx.x;
    const int lane = threadIdx.x;
    const float* maxc_p = (const float*)(ws + WS_MAXC);
    float* fscore = (float*)(ws + WS_FSCORE);

    __shared__ float mx0[CAPC], mx1[CAPC], mx2[CAPC], mx3[CAPC], msc[CAPC];
    __shared__ unsigned short mgid[CAPC];
    __shared__ float D[DCAP * DSTR];

    const float maxcp1 = maxc_p[0] + 1.0f;
    const float off = (float)c * maxcp1;

    // stage all idx chunks into registers (loads overlap), then ballot-compact
    int myidx[NCHK];
#pragma unroll
    for (int t = 0; t < NCHK; t++) {
        int k = t * 64 + lane;
        myidx[t] = (k < n) ? idxs[k] : -1;
    }
    int base = 0;
#pragma unroll
    for (int t = 0; t < NCHK; t++) {
        bool p = (myidx[t] == c);
        unsigned long long m = __ballot(p);
        if (p) {
            int pos = base + __popcll(m & ((1ull << lane) - 1ull));
            if (pos < CAPC) {
                int k = t * 64 + lane;
                float4 bb = ((const float4*)boxes)[k];
                mx0[pos] = bb.x + off; mx1[pos] = bb.y + off;
                mx2[pos] = bb.z + off; mx3[pos] = bb.w + off;
                msc[pos] = scores[k];
                mgid[pos] = (unsigned short)k;
            }
        }
        base += __popcll(m);
    }
    int cnt = base < CAPC ? base : CAPC;
    __syncthreads();

    if (cnt <= 64) {
        // ======== fast path: one member per lane ========
        const bool v0 = lane < cnt;
        float c0 = 0, c1 = 0, c2 = 0, c3 = 0;
        if (v0) { c0 = mx0[lane]; c1 = mx1[lane]; c2 = mx2[lane]; c3 = mx3[lane]; }
        const float ab = (c2 - c0) * (c3 - c1);
        // precompute decay matrix rows (independent -> exp latency overlapped)
        for (int i = 0; i < cnt; i++) {
            float w0 = mx0[i], w1 = mx1[i], w2 = mx2[i], w3 = mx3[i];
            float aw = (w2 - w0) * (w3 - w1);
            float x1 = fmaxf(w0, c0), y1 = fmaxf(w1, c1);
            float x2 = fminf(w2, c2), y2 = fminf(w3, c3);
            float iw = fmaxf(x2 - x1, 0.f), ih = fmaxf(y2 - y1, 0.f);
            float inter = iw * ih;
            float d = 1.0f;                     // exp(-0.0) == 1.0f exactly
            if (inter != 0.f) {
                float iou = inter / ((aw + ab) - inter);
                float arg = -(iou * iou) / 0.5f;
                d = (float)exp((double)arg);
            }
            D[i * 64 + lane] = d;
        }
        __syncthreads();

        float sc = v0 ? msc[lane] : -1.f;
        int   g  = v0 ? mgid[lane] : 0;
        float frz = 0.f;
        for (int s = 0; s < cnt; s++) {
            float M = wave_max64(sc);
            unsigned long long bal = __ballot(sc == M);
            int wm = __ffsll(bal) - 1;          // lowest lane = lowest orig index
            float d = D[wm * 64 + lane];
            if (lane == wm) { frz = M; sc = -1.f; }
            else if (sc >= 0.f) sc = sc * d;    // same values, same order -> bit-exact
        }
        if (v0) fscore[g] = frz;
    } else {
        // ======== fallback (cnt > 64): validated 2-slot in-loop path ========
        float sc0 = -1.f, sc1 = -1.f;
        float a0 = 0, a1 = 0, a2 = 0, a3 = 0, b0 = 0, b1 = 0, b2 = 0, b3 = 0;
        int g0 = 0, g1 = 0;
        if (lane < cnt) {
            sc0 = msc[lane];
            a0 = mx0[lane]; a1 = mx1[lane]; a2 = mx2[lane]; a3 = mx3[lane];
            g0 = mgid[lane];
        }
        if (64 + lane < cnt) {
            sc1 = msc[64 + lane];
            b0 = mx0[64 + lane]; b1 = mx1[64 + lane]; b2 = mx2[64 + lane]; b3 = mx3[64 + lane];
            g1 = mgid[64 + lane];
        }
        for (int s = 0; s < cnt; s++) {
            float M = fmaxf(sc0, sc1);
            for (int o = 32; o >= 1; o >>= 1) M = fmaxf(M, __shfl_xor(M, o, 64));
            unsigned long long balA = __ballot(sc0 == M);
            int wm;
            if (balA) wm = __ffsll(balA) - 1;
            else      wm = 64 + __ffsll(__ballot(sc1 == M)) - 1;
            float w0 = mx0[wm], w1 = mx1[wm], w2 = mx2[wm], w3 = mx3[wm];
            if (wm == lane)           { fscore[g0] = M; sc0 = -1.f; }
            else if (wm == 64 + lane) { fscore[g1] = M; sc1 = -1.f; }
            float area_w = (w2 - w0) * (w3 - w1);
            if (sc0 >= 0.f) {
                float x1 = fmaxf(w0, a0), y1 = fmaxf(w1, a1);
                float x2 = fminf(w2, a2), y2 = fminf(w3, a3);
                float iw = fmaxf(x2 - x1, 0.f), ih = fmaxf(y2 - y1, 0.f);
                float inter = iw * ih;
                float area_b = (a2 - a0) * (a3 - a1);
                float iou = inter / ((area_w + area_b) - inter);
                float arg = -(iou * iou) / 0.5f;
                sc0 = sc0 * (float)exp((double)arg);
            }
            if (sc1 >= 0.f) {
                float x1 = fmaxf(w0, b0), y1 = fmaxf(w1, b1);
                float x2 = fminf(w2, b2), y2 = fminf(w3, b3);
                float iw = fmaxf(x2 - x1, 0.f), ih = fmaxf(y2 - y1, 0.f);
                float inter = iw * ih;
                float area_b = (b2 - b0) * (b3 - b1);
                float iou = inter / ((area_w + area_b) - inter);
                float arg = -(iou * iou) / 0.5f;
                sc1 = sc1 * (float)exp((double)arg);
            }
        }
    }
}

// ---------------- kernel 2: partial rank counts (j-split) ----------------
__global__ void __launch_bounds__(256)
partial_rank_kernel(char* __restrict__ ws, int n) {
    __shared__ float sv[JCH];
    const float* fscore = (const float*)(ws + WS_FSCORE);
    unsigned* GT   = (unsigned*)(ws + WS_GT);
    unsigned* EQLT = (unsigned*)(ws + WS_EQLT);
    unsigned* EQ   = (unsigned*)(ws + WS_EQ);

    const int chunk = (n + JC - 1) / JC;
    const int j0 = blockIdx.y * chunk;
    const int jn = min(n - j0, chunk);
    for (int j = threadIdx.x; j < jn; j += 256) sv[j] = fscore[j0 + j];
    __syncthreads();

    int i = blockIdx.x * 256 + threadIdx.x;
    if (i < n) {
        float s = fscore[i];
        int gt = 0, eq = 0, eqlt = 0;
        for (int jj = 0; jj < jn; jj++) {
            float x = sv[jj];
            gt   += (x > s) ? 1 : 0;
            eq   += (x == s) ? 1 : 0;
            eqlt += (x == s && (j0 + jj) < i) ? 1 : 0;
        }
        atomicAdd(GT + i,   (unsigned)gt);
        atomicAdd(EQLT + i, (unsigned)eqlt);
        atomicAdd(EQ + i,   (unsigned)eq);
    }
}

// ---------------- kernel 3: scatter + tie fix-up walk + emit ----------------
__global__ void __launch_bounds__(64)
finalize_kernel(char* __restrict__ ws, float* __restrict__ out, int n) {
    __shared__ unsigned short ordL[NMAX];
    __shared__ float          svL[NMAX];
    __shared__ unsigned short slotL[NMAX];
    __shared__ unsigned short batL[NMAX];
    __shared__ unsigned char  tieL[NMAX];
    __shared__ int rstop_s;

    const float* fscore = (const float*)(ws + WS_FSCORE);
    const unsigned* GT   = (const unsigned*)(ws + WS_GT);
    const unsigned* EQLT = (const unsigned*)(ws + WS_EQLT);
    const unsigned* EQ   = (const unsigned*)(ws + WS_EQ);
    const int lane = threadIdx.x;

    int myflag = 0;
    for (int b = lane; b < n; b += 64) {
        unsigned gt = GT[b], eqlt = EQLT[b], eq = EQ[b];
        int r = (int)(gt + eqlt);
        ordL[r] = (unsigned short)b;
        svL[r] = fscore[b];
        slotL[b] = (unsigned short)b;
        batL[b]  = (unsigned short)b;
        myflag |= (eq >= 2 && (unsigned)b < gt + eq) ? 1 : 0;
    }
    const int flag = (__ballot(myflag) != 0ull);
    __syncthreads();

    int rmax = -1;
    for (int r = lane; r < n; r += 64) {
        unsigned char t = (r + 1 < n) && (svL[r] == svL[r + 1]);
        tieL[r] = t;
        if (t) rmax = r;
    }
    for (int o = 32; o >= 1; o >>= 1) rmax = max(rmax, __shfl_xor(rmax, o, 64));
    if (lane == 0) rstop_s = rmax + 2;
    __syncthreads();

    if (flag && lane == 0) {
        const int rstop = rstop_s;
        int r = 0;
        while (r < rstop) {
            if (!tieL[r]) {
                int w = ordL[r];
                int j = slotL[w];
                int d = batL[r];
                batL[j] = (unsigned short)d;
                slotL[d] = (unsigned short)j;
                r++;
            } else {
                int g = 1;
                while (tieL[r + g - 1]) g++;
                for (int t = 0; t < g; t++) {
                    int bi = r + t;
                    int bs = slotL[ordL[bi]];
                    for (int q = r + t + 1; q < r + g; q++) {
                        int s2 = slotL[ordL[q]];
                        if (s2 < bs) { bs = s2; bi = q; }
                    }
                    unsigned short w = ordL[bi];
                    ordL[bi] = ordL[r + t];
                    ordL[r + t] = w;
                    int d = batL[r + t];
                    batL[bs] = (unsigned short)d;
                    slotL[d] = (unsigned short)bs;
                }
                r += g;
            }
        }
    }
    __syncthreads();

    for (int r = lane; r < n; r += 64) {
        float s = svL[r];
        out[r] = s;
        out[n + r] = (float)ordL[r];
        out[2 * n + r] = (s > 0.05f) ? 1.f : 0.f;
    }
}

extern "C" void kernel_launch(void* const* d_in, const int* in_sizes, int n_in,
                              void* d_out, int out_size, void* d_ws, size_t ws_size,
                              hipStream_t stream) {
    const float* boxes  = (const float*)d_in[0];  // [N,4] f32
    const float* scores = (const float*)d_in[1];  // [N]   f32
    const int*   idxs   = (const int*)d_in[2];    // [N]   i32
    float* out = (float*)d_out;                   // scores | order | keep (f32)
    char* ws = (char*)d_ws;
    const int n = in_sizes[1];

    max_kernel<<<1, 256, 0, stream>>>(boxes, n * 4, ws);
    nms_class_kernel<<<NCLS, 64, 0, stream>>>(boxes, scores, idxs, ws, n);
    dim3 rgrid((n + 255) / 256, JC);
    partial_rank_kernel<<<rgrid, 256, 0, stream>>>(ws, n);
    finalize_kernel<<<1, 64, 0, stream>>>(ws, out, n);
}